// Round 9
// baseline (195.842 us; speedup 1.0000x reference)
//
#include <hip/hip_runtime.h>
#include <hip/hip_bf16.h>
#include <cstdint>

#define IN_CH 512
#define OUT_CH 512
#define STYLE_DIM 512
#define BATCH 8
#define HW 64

typedef __bf16 bf16x8 __attribute__((ext_vector_type(8)));
typedef float f32x16 __attribute__((ext_vector_type(16)));

__device__ __forceinline__ void gload_lds16(const void* g, void* l) {
  __builtin_amdgcn_global_load_lds(
      (const __attribute__((address_space(1))) unsigned int*)g,
      (__attribute__((address_space(3))) unsigned int*)l,
      16, 0, 0);
}

#define WAITV(N) asm volatile("s_waitcnt vmcnt(" #N ")" ::: "memory")
#define SB0() __builtin_amdgcn_sched_barrier(0)
#define BARRIER() do { asm volatile("" ::: "memory"); __builtin_amdgcn_s_barrier(); \
                       asm volatile("" ::: "memory"); } while (0)

// ---------------- prepass 1: s[b][ic] ----------------
__global__ void k_style(const float* __restrict__ style, const float* __restrict__ modw,
                        const float* __restrict__ modb, float* __restrict__ s_out) {
  __shared__ float st[BATCH * STYLE_DIM];
  const int tid = threadIdx.x;
  for (int i = tid; i < BATCH * STYLE_DIM; i += 256) st[i] = style[i];
  __syncthreads();
  const int ic = blockIdx.x * 4 + (tid >> 6);
  const int l = tid & 63;
  const float* mr = modw + (size_t)ic * STYLE_DIM + l * 8;
  float m[8];
  #pragma unroll
  for (int j = 0; j < 8; ++j) m[j] = mr[j];
  float accs[8];
  #pragma unroll
  for (int b = 0; b < 8; ++b) {
    const float* sb = st + b * STYLE_DIM + l * 8;
    float a = 0.f;
    #pragma unroll
    for (int j = 0; j < 8; ++j) a += m[j] * sb[j];
    accs[b] = a;
  }
  #pragma unroll
  for (int off = 32; off; off >>= 1) {
    #pragma unroll
    for (int b = 0; b < 8; ++b) accs[b] += __shfl_down(accs[b], off, 64);
  }
  if (l == 0) {
    #pragma unroll
    for (int b = 0; b < 8; ++b)
      s_out[b * IN_CH + ic] = accs[b] * 0.04419417382415922f + modb[ic];
  }
}

// ---------------- prepass 2: wsq + bf16 W, ic pre-swizzled by (oc&7) -------------------
__global__ void k_wprep(const float* __restrict__ w, float* __restrict__ wsq,
                        __bf16* __restrict__ wb) {
  const int idx = blockIdx.x * 256 + threadIdx.x;
  const int oc = idx >> 9, ic = idx & 511;
  const float* p = w + ((size_t)oc * IN_CH + ic) * 9;
  const int icw = ic ^ ((oc & 7) << 3);
  float sum = 0.f;
  #pragma unroll
  for (int t = 0; t < 9; ++t) {
    float v = p[t];
    sum += v * v;
    wb[((size_t)(t * OUT_CH) + oc) * IN_CH + icw] = (__bf16)v;
  }
  wsq[oc * IN_CH + ic] = sum;
}

// ---------------- prepass 3: demod scale ----------------
__global__ void k_demod(const float* __restrict__ s, const float* __restrict__ wsq,
                        float* __restrict__ scale) {
  const int oc = blockIdx.x;
  const int l = threadIdx.x;
  const float* wr = wsq + (size_t)oc * IN_CH + l * 8;
  float w8[8];
  #pragma unroll
  for (int j = 0; j < 8; ++j) w8[j] = wr[j];
  #pragma unroll
  for (int b = 0; b < 8; ++b) {
    const float* sb = s + b * IN_CH + l * 8;
    float acc = 0.f;
    #pragma unroll
    for (int j = 0; j < 8; ++j) { float sv = sb[j]; acc += sv * sv * w8[j]; }
    #pragma unroll
    for (int off = 32; off; off >>= 1) acc += __shfl_down(acc, off, 64);
    if (l == 0)
      scale[b * OUT_CH + oc] =
          rsqrtf(acc * (1.0f / 4608.0f) + 1e-8f) * 0.014731391274719732f;
  }
}

// ---------------- prepass 4: xg[b][ug][y][x][8] = bf16(x * s) ----------------
__global__ void k_xprep(const float* __restrict__ x, const float* __restrict__ s,
                        __bf16* __restrict__ xg) {
  const int b = blockIdx.x >> 6, y = blockIdx.x & 63;
  const int w = threadIdx.x >> 6, lane = threadIdx.x & 63;
  const float* sr = s + b * IN_CH;
  #pragma unroll
  for (int it = 0; it < 8; ++it) {
    const int ug = it * 8 + w;
    bf16x8 pk;
    #pragma unroll
    for (int j = 0; j < 8; ++j) {
      const int ic = ug * 8 + j;
      pk[j] = (__bf16)(x[(((size_t)(b * IN_CH) + ic) * HW + y) * HW + lane] * sr[ic]);
    }
    *(bf16x8*)(xg + ((((size_t)(b * 64 + ug) * HW + y) * HW + lane) * 8)) = pk;
  }
}

// ---------------- main conv: r8 schedule + pinned 2-batch read/MFMA overlap --------------
// Per step: [reads ks01 | stage_w | reads ks23 | SB0 | MFMA ks01 | MFMA ks23].
// Compiler's fine lgkmcnt lets MFMA01 run while port drains reads23 -> LDS/MFMA overlap
// within each wave instead of phase-serializing across the whole block.
__global__ __launch_bounds__(512, 2) void k_conv(
    const __bf16* __restrict__ Wg,   // [9][512][512] ic pre-swizzled by (oc&7)
    const __bf16* __restrict__ Xg,   // [8][64 ug][64 y][64 x][8]
    const float* __restrict__ scale, // [8][512] = demod*cs
    float* __restrict__ out)         // [8][512][64][64]
{
  __shared__ __attribute__((aligned(16))) __bf16 Xs[6 * 66 * 64];   // 50688 B
  __shared__ __attribute__((aligned(16))) __bf16 Wl[3][256 * 64];   // 98304 B
  __shared__ __attribute__((aligned(16))) __bf16 Dump[4096];        // 8192 B OOR sink

  const int tid = threadIdx.x;
  const int lane = tid & 63;
  const int wid = tid >> 6;
  const int wm = wid >> 2;      // oc half
  const int wn = wid & 3;       // image row within tile
  const int ln31 = lane & 31;
  const int laneK = lane >> 5;

  const int bid0 = blockIdx.x;
  const int bid = (bid0 & 7) * 32 + (bid0 >> 3);   // XCD-chunked swizzle
  const int octile = bid & 1;
  const int ptile = (bid >> 1) & 15;
  const int b = bid >> 5;
  const int oc0 = octile * 256;
  const int r0 = ptile * 4;

  auto stage_w = [&](int chunkv, int tapv, int bsel) {  // 4 gload16/thread = 32 KB
    const int ic0 = chunkv * 64;
    #pragma unroll
    for (int i = 0; i < 4; ++i) {
      const int sidx = tid + 512 * i;
      const int oc = sidx >> 3, u = sidx & 7;
      gload_lds16(Wg + (((size_t)(tapv * OUT_CH) + oc0 + oc) * IN_CH + ic0 + u * 8),
                  &Wl[bsel][oc * 64 + u * 8]);
    }
  };
  auto stage_x = [&](int chunkv) {   // ALWAYS 6 gload16/thread (fixed vmcnt bookkeeping)
    const int col = tid >> 3;        // 0..63
    const int u = tid & 7;
    const int ug = chunkv * 8 + (u ^ ((col + 1) & 7));   // swizzle via global src addr
    #pragma unroll
    for (int j = 0; j < 6; ++j) {
      const int y = r0 - 1 + j;
      const bool ok = (y >= 0 && y < HW);
      const int yc = ok ? y : 0;
      void* dst = ok ? (void*)&Xs[(j * 66 + col + 1) * 64 + u * 8]
                     : (void*)&Dump[tid * 8];            // base + lane*16
      gload_lds16(Xg + ((((size_t)(b * 64 + ug) * HW + yc) * HW + col) * 8), dst);
    }
  };

  // zero Xs once (halo rows/cols = conv zero-padding; OOR restages go to Dump)
  {
    float4 z = {0.f, 0.f, 0.f, 0.f};
    float4* p = (float4*)Xs;
    for (int i = tid; i < 6 * 66 * 64 / 8; i += 512) p[i] = z;
  }
  __syncthreads();
  stage_x(0);               // X0(6)
  stage_w(0, 0, 0);         // +W0(4)
  stage_w(0, 1, 1);         // +W1(4) -> queue [X0,W0,W1]; s=0's WAITV(4) drains X0+W0
  f32x16 acc[4][2] = {};
  const int akey8 = (ln31 & 7) << 3;
  const int kb = laneK * 8;

  int tap = 0, chunk = 0, wbuf = 0;

  for (int s = 0; s < 72; ++s) {
    // steady: [W(s),W(s+1)]; tap0: [W(s),X(c),W(s+1)]; WAITV(4) keeps newest 4 = W(s+1)
    if (s == 71) { WAITV(0); } else { WAITV(4); }
    BARRIER();

    const int dy = tap / 3 - 1, dx = tap % 3 - 1;
    const int xrow = wn + 1 + dy;
    const int col0 = ln31 + 1 + dx;
    const int bkey8 = (col0 & 7) << 3;
    const __bf16* __restrict__ wbase = &Wl[wbuf][(128 * wm + ln31) * 64];
    const __bf16* __restrict__ xb0 = &Xs[(xrow * 66 + col0) * 64];

    // ---- batch 1 reads (ks 0,1): 12 ds_read_b128 ----
    bf16x8 av01[2][4], bv01[2][2];
    #pragma unroll
    for (int kk = 0; kk < 2; ++kk) {
      const int ael = (kk * 16 + kb) ^ akey8;
      const int bel = (kk * 16 + kb) ^ bkey8;
      #pragma unroll
      for (int mf = 0; mf < 4; ++mf) av01[kk][mf] = *(const bf16x8*)(wbase + mf * 2048 + ael);
      bv01[kk][0] = *(const bf16x8*)(xb0 + bel);
      bv01[kk][1] = *(const bf16x8*)(xb0 + 32 * 64 + bel);
    }

    // ---- W prefetch issue (VMEM, overlaps everything below) ----
    const int wb2 = (wbuf >= 1) ? wbuf - 1 : wbuf + 2;   // (wbuf+2)%3
    const bool xboundary = (tap == 8 && chunk < 7);
    if (!xboundary && s + 2 < 72) {
      int t2 = tap + 2, c2 = chunk;
      if (t2 >= 9) { t2 -= 9; ++c2; }
      stage_w(c2, t2, wb2);
    }

    // ---- batch 2 reads (ks 2,3): 12 ds_read_b128 ----
    bf16x8 av23[2][4], bv23[2][2];
    #pragma unroll
    for (int kk = 0; kk < 2; ++kk) {
      const int ael = ((kk + 2) * 16 + kb) ^ akey8;
      const int bel = ((kk + 2) * 16 + kb) ^ bkey8;
      #pragma unroll
      for (int mf = 0; mf < 4; ++mf) av23[kk][mf] = *(const bf16x8*)(wbase + mf * 2048 + ael);
      bv23[kk][0] = *(const bf16x8*)(xb0 + bel);
      bv23[kk][1] = *(const bf16x8*)(xb0 + 32 * 64 + bel);
    }
    SB0();   // pin: all reads + stage issued before any MFMA

    // ---- MFMA batch 1 (compiler waits only on batch-1 reads; batch-2 drains in port) ----
    __builtin_amdgcn_s_setprio(1);
    #pragma unroll
    for (int kk = 0; kk < 2; ++kk) {
      #pragma unroll
      for (int mf = 0; mf < 4; ++mf) {
        acc[mf][0] = __builtin_amdgcn_mfma_f32_32x32x16_bf16(av01[kk][mf], bv01[kk][0], acc[mf][0], 0, 0, 0);
        acc[mf][1] = __builtin_amdgcn_mfma_f32_32x32x16_bf16(av01[kk][mf], bv01[kk][1], acc[mf][1], 0, 0, 0);
      }
    }
    // ---- MFMA batch 2 ----
    #pragma unroll
    for (int kk = 0; kk < 2; ++kk) {
      #pragma unroll
      for (int mf = 0; mf < 4; ++mf) {
        acc[mf][0] = __builtin_amdgcn_mfma_f32_32x32x16_bf16(av23[kk][mf], bv23[kk][0], acc[mf][0], 0, 0, 0);
        acc[mf][1] = __builtin_amdgcn_mfma_f32_32x32x16_bf16(av23[kk][mf], bv23[kk][1], acc[mf][1], 0, 0, 0);
      }
    }
    __builtin_amdgcn_s_setprio(0);

    if (xboundary) {
      BARRIER();                 // all waves done reading Xs
      stage_x(chunk + 1);        // new X first (older in queue than W(s+2))
      stage_w(chunk + 1, 1, wb2);
    }

    if (++tap == 9) { tap = 0; ++chunk; }
    wbuf = (wbuf == 2) ? 0 : wbuf + 1;
  }

  // epilogue: out = acc * (demod*cs), NCHW
  const int y = r0 + wn;
  #pragma unroll
  for (int mf = 0; mf < 4; ++mf) {
    #pragma unroll
    for (int reg = 0; reg < 16; ++reg) {
      const int rowid = (reg & 3) + 8 * (reg >> 2) + 4 * laneK;
      const int oc = oc0 + 128 * wm + 32 * mf + rowid;
      const float sc = scale[b * OUT_CH + oc];
      float* op = out + (((size_t)(b * OUT_CH + oc) * HW + y) * HW) + ln31;
      op[0] = acc[mf][0][reg] * sc;
      op[32] = acc[mf][1][reg] * sc;
    }
  }
}

// ---------------- launcher ---------------------------------------------------------------
extern "C" void kernel_launch(void* const* d_in, const int* in_sizes, int n_in,
                              void* d_out, int out_size, void* d_ws, size_t ws_size,
                              hipStream_t stream) {
  const float* x      = (const float*)d_in[0];
  const float* style  = (const float*)d_in[1];
  const float* weight = (const float*)d_in[2];
  const float* modw   = (const float*)d_in[3];
  const float* modb   = (const float*)d_in[4];
  float* out = (float*)d_out;

  char* ws = (char*)d_ws;
  float*  s_buf = (float*)(ws + 0);
  float*  scale = (float*)(ws + 16384);
  float*  wsq   = (float*)(ws + 32768);
  __bf16* wb    = (__bf16*)(ws + 32768 + 1048576);
  __bf16* xg    = (__bf16*)(ws + 32768 + 1048576 + 9 * OUT_CH * IN_CH * 2);

  k_style<<<128, 256, 0, stream>>>(style, modw, modb, s_buf);
  k_wprep<<<1024, 256, 0, stream>>>(weight, wsq, wb);
  k_demod<<<512, 64, 0, stream>>>(s_buf, wsq, scale);
  k_xprep<<<BATCH * HW, 512, 0, stream>>>(x, s_buf, xg);
  k_conv<<<256, 512, 0, stream>>>(wb, xg, scale, out);
}

// Round 10
// 191.636 us; speedup vs baseline: 1.0220x; 1.0220x over previous
//
#include <hip/hip_runtime.h>
#include <hip/hip_bf16.h>
#include <cstdint>

#define IN_CH 512
#define OUT_CH 512
#define STYLE_DIM 512
#define BATCH 8
#define HW 64

typedef __bf16 bf16x8 __attribute__((ext_vector_type(8)));
typedef float f32x16 __attribute__((ext_vector_type(16)));

__device__ __forceinline__ void gload_lds16(const void* g, void* l) {
  __builtin_amdgcn_global_load_lds(
      (const __attribute__((address_space(1))) unsigned int*)g,
      (__attribute__((address_space(3))) unsigned int*)l,
      16, 0, 0);
}

#define WAITV(N) asm volatile("s_waitcnt vmcnt(" #N ")" ::: "memory")
#define BARRIER() do { asm volatile("" ::: "memory"); __builtin_amdgcn_s_barrier(); \
                       asm volatile("" ::: "memory"); } while (0)

// ---------------- prepass 1: s[b][ic] ----------------
__global__ void k_style(const float* __restrict__ style, const float* __restrict__ modw,
                        const float* __restrict__ modb, float* __restrict__ s_out) {
  __shared__ float st[BATCH * STYLE_DIM];
  const int tid = threadIdx.x;
  for (int i = tid; i < BATCH * STYLE_DIM; i += 256) st[i] = style[i];
  __syncthreads();
  const int ic = blockIdx.x * 4 + (tid >> 6);
  const int l = tid & 63;
  const float* mr = modw + (size_t)ic * STYLE_DIM + l * 8;
  float m[8];
  #pragma unroll
  for (int j = 0; j < 8; ++j) m[j] = mr[j];
  float accs[8];
  #pragma unroll
  for (int b = 0; b < 8; ++b) {
    const float* sb = st + b * STYLE_DIM + l * 8;
    float a = 0.f;
    #pragma unroll
    for (int j = 0; j < 8; ++j) a += m[j] * sb[j];
    accs[b] = a;
  }
  #pragma unroll
  for (int off = 32; off; off >>= 1) {
    #pragma unroll
    for (int b = 0; b < 8; ++b) accs[b] += __shfl_down(accs[b], off, 64);
  }
  if (l == 0) {
    #pragma unroll
    for (int b = 0; b < 8; ++b)
      s_out[b * IN_CH + ic] = accs[b] * 0.04419417382415922f + modb[ic];
  }
}

// ---------------- prepass 2: wsq + bf16 W, ic pre-swizzled by (oc&7) -------------------
__global__ void k_wprep(const float* __restrict__ w, float* __restrict__ wsq,
                        __bf16* __restrict__ wb) {
  const int idx = blockIdx.x * 256 + threadIdx.x;
  const int oc = idx >> 9, ic = idx & 511;
  const float* p = w + ((size_t)oc * IN_CH + ic) * 9;
  const int icw = ic ^ ((oc & 7) << 3);
  float sum = 0.f;
  #pragma unroll
  for (int t = 0; t < 9; ++t) {
    float v = p[t];
    sum += v * v;
    wb[((size_t)(t * OUT_CH) + oc) * IN_CH + icw] = (__bf16)v;
  }
  wsq[oc * IN_CH + ic] = sum;
}

// ---------------- prepass 3: demod scale ----------------
__global__ void k_demod(const float* __restrict__ s, const float* __restrict__ wsq,
                        float* __restrict__ scale) {
  const int oc = blockIdx.x;
  const int l = threadIdx.x;
  const float* wr = wsq + (size_t)oc * IN_CH + l * 8;
  float w8[8];
  #pragma unroll
  for (int j = 0; j < 8; ++j) w8[j] = wr[j];
  #pragma unroll
  for (int b = 0; b < 8; ++b) {
    const float* sb = s + b * IN_CH + l * 8;
    float acc = 0.f;
    #pragma unroll
    for (int j = 0; j < 8; ++j) { float sv = sb[j]; acc += sv * sv * w8[j]; }
    #pragma unroll
    for (int off = 32; off; off >>= 1) acc += __shfl_down(acc, off, 64);
    if (l == 0)
      scale[b * OUT_CH + oc] =
          rsqrtf(acc * (1.0f / 4608.0f) + 1e-8f) * 0.014731391274719732f;
  }
}

// ---------------- prepass 4: xg[b][ug][y][x][8] = bf16(x * s) ----------------
__global__ void k_xprep(const float* __restrict__ x, const float* __restrict__ s,
                        __bf16* __restrict__ xg) {
  const int b = blockIdx.x >> 6, y = blockIdx.x & 63;
  const int w = threadIdx.x >> 6, lane = threadIdx.x & 63;
  const float* sr = s + b * IN_CH;
  #pragma unroll
  for (int it = 0; it < 8; ++it) {
    const int ug = it * 8 + w;
    bf16x8 pk;
    #pragma unroll
    for (int j = 0; j < 8; ++j) {
      const int ic = ug * 8 + j;
      pk[j] = (__bf16)(x[(((size_t)(b * IN_CH) + ic) * HW + y) * HW + lane] * sr[ic]);
    }
    *(bf16x8*)(xg + ((((size_t)(b * 64 + ug) * HW + y) * HW + lane) * 8)) = pk;
  }
}

// ---------------- main conv: r8 + precomputed addresses + 1-ks-ahead rotation ------------
// Full tap unroll -> all geometry compile-time. Two 6-fragment sets rotate: MFMA(ks)
// overlaps port drain of reads(ks+1); cross-tap read-ahead keeps pipe full over barriers.
__global__ __launch_bounds__(512, 2) void k_conv(
    const __bf16* __restrict__ Wg,   // [9][512][512] ic pre-swizzled by (oc&7)
    const __bf16* __restrict__ Xg,   // [8][64 ug][64 y][64 x][8]
    const float* __restrict__ scale, // [8][512] = demod*cs
    float* __restrict__ out)         // [8][512][64][64]
{
  __shared__ __attribute__((aligned(16))) __bf16 Xs[6 * 66 * 64];   // 50688 B
  __shared__ __attribute__((aligned(16))) __bf16 Wl[3][256 * 64];   // 98304 B
  __shared__ __attribute__((aligned(16))) __bf16 Dump[4096];        // 8192 B OOR sink

  const int tid = threadIdx.x;
  const int lane = tid & 63;
  const int wid = tid >> 6;
  const int wm = wid >> 2;      // oc half
  const int wn = wid & 3;       // image row within tile
  const int ln31 = lane & 31;
  const int laneK = lane >> 5;

  const int bid0 = blockIdx.x;
  const int bid = (bid0 & 7) * 32 + (bid0 >> 3);   // XCD-chunked swizzle
  const int octile = bid & 1;
  const int ptile = (bid >> 1) & 15;
  const int b = bid >> 5;
  const int oc0 = octile * 256;
  const int r0 = ptile * 4;

  auto stage_w = [&](int chunkv, int tapv, int bsel) {  // 4 gload16/thread = 32 KB
    const int ic0 = chunkv * 64;
    #pragma unroll
    for (int i = 0; i < 4; ++i) {
      const int sidx = tid + 512 * i;
      const int oc = sidx >> 3, u = sidx & 7;
      gload_lds16(Wg + (((size_t)(tapv * OUT_CH) + oc0 + oc) * IN_CH + ic0 + u * 8),
                  &Wl[bsel][oc * 64 + u * 8]);
    }
  };
  auto stage_x = [&](int chunkv) {   // ALWAYS 6 gload16/thread (fixed vmcnt bookkeeping)
    const int col = tid >> 3;        // 0..63
    const int u = tid & 7;
    const int ug = chunkv * 8 + (u ^ ((col + 1) & 7));
    #pragma unroll
    for (int j = 0; j < 6; ++j) {
      const int y = r0 - 1 + j;
      const bool ok = (y >= 0 && y < HW);
      const int yc = ok ? y : 0;
      void* dst = ok ? (void*)&Xs[(j * 66 + col + 1) * 64 + u * 8]
                     : (void*)&Dump[tid * 8];
      gload_lds16(Xg + ((((size_t)(b * 64 + ug) * HW + yc) * HW + col) * 8), dst);
    }
  };

  // zero Xs once (halo rows/cols = conv zero-padding)
  {
    float4 z = {0.f, 0.f, 0.f, 0.f};
    float4* p = (float4*)Xs;
    for (int i = tid; i < 6 * 66 * 64 / 8; i += 512) p[i] = z;
  }
  __syncthreads();
  stage_x(0);               // X0(6)
  stage_w(0, 0, 0);         // +W0(4)
  stage_w(0, 1, 1);         // +W1(4); drained by first tap's WAITV(0)

  // ---- precomputed addressing (all loop-invariant; arrays only const-indexed) ----
  const int akey8 = (ln31 & 7) << 3;
  const int kb = laneK * 8;
  const __bf16* wbase[3];
  #pragma unroll
  for (int i = 0; i < 3; ++i) wbase[i] = &Wl[i][(128 * wm + ln31) * 64];
  const __bf16* xbt[9];
  #pragma unroll
  for (int t = 0; t < 9; ++t) {
    const int dy = t / 3 - 1, dx = t % 3 - 1;
    xbt[t] = &Xs[((wn + 1 + dy) * 66 + (ln31 + 1 + dx)) * 64];
  }
  int aoffe[4];
  #pragma unroll
  for (int ks = 0; ks < 4; ++ks) aoffe[ks] = (ks * 16 + kb) ^ akey8;
  int bele[3][4];
  #pragma unroll
  for (int dxi = 0; dxi < 3; ++dxi) {
    const int bkey8 = ((ln31 + dxi) & 7) << 3;   // col0 = ln31 + 1 + (dxi-1)
    #pragma unroll
    for (int ks = 0; ks < 4; ++ks) bele[dxi][ks] = (ks * 16 + kb) ^ bkey8;
  }

  f32x16 acc[4][2] = {};
  bf16x8 Aa[4], Ab[2], Ba[4], Bb[2];

#define RDA(P, KS, BUF) { _Pragma("unroll") for (int mf = 0; mf < 4; ++mf) \
    P##a[mf] = *(const bf16x8*)(wbase[BUF] + aoffe[KS] + mf * 2048); }
#define RDB(P, TAP, KS) { const __bf16* p_ = xbt[TAP] + bele[(TAP) % 3][KS]; \
    P##b[0] = *(const bf16x8*)p_; P##b[1] = *(const bf16x8*)(p_ + 2048); }
#define MM(P) { __builtin_amdgcn_s_setprio(1); \
    _Pragma("unroll") for (int mf = 0; mf < 4; ++mf) { \
      acc[mf][0] = __builtin_amdgcn_mfma_f32_32x32x16_bf16(P##a[mf], P##b[0], acc[mf][0], 0, 0, 0); \
      acc[mf][1] = __builtin_amdgcn_mfma_f32_32x32x16_bf16(P##a[mf], P##b[1], acc[mf][1], 0, 0, 0); } \
    __builtin_amdgcn_s_setprio(0); }

#define TAPBODY(T) { \
    WAITV(0); BARRIER(); \
    if ((T) == 0) { RDA(A, 0, 0) RDB(A, 0, 0) }            /* cold ks0 (new chunk) */ \
    RDA(B, 1, (T) % 3) RDB(B, (T), 1)                       /* reads for ks1 */ \
    MM(A)                                                   /* ks0 */ \
    if ((T) <= 6)      stage_w(c,     (T) + 2, ((T) + 2) % 3); \
    else if (c < 7)    stage_w(c + 1, (T) - 7, ((T) + 2) % 3); \
    RDA(A, 2, (T) % 3) RDB(A, (T), 2)                       /* reads for ks2 */ \
    MM(B)                                                   /* ks1 */ \
    RDA(B, 3, (T) % 3) RDB(B, (T), 3)                       /* reads for ks3 */ \
    MM(A)                                                   /* ks2 */ \
    if ((T) < 8) { RDA(A, 0, ((T) + 1) % 3) RDB(A, (T) + 1, 0) }  /* read-ahead */ \
    MM(B)                                                   /* ks3 */ \
    if ((T) == 8) { BARRIER(); if (c < 7) stage_x(c + 1); } \
  }

  #pragma unroll 1
  for (int c = 0; c < 8; ++c) {
    TAPBODY(0) TAPBODY(1) TAPBODY(2)
    TAPBODY(3) TAPBODY(4) TAPBODY(5)
    TAPBODY(6) TAPBODY(7) TAPBODY(8)
  }

  // epilogue: out = acc * (demod*cs), NCHW
  const int y = r0 + wn;
  #pragma unroll
  for (int mf = 0; mf < 4; ++mf) {
    #pragma unroll
    for (int reg = 0; reg < 16; ++reg) {
      const int rowid = (reg & 3) + 8 * (reg >> 2) + 4 * laneK;
      const int oc = oc0 + 128 * wm + 32 * mf + rowid;
      const float sc = scale[b * OUT_CH + oc];
      float* op = out + (((size_t)(b * OUT_CH + oc) * HW + y) * HW) + ln31;
      op[0] = acc[mf][0][reg] * sc;
      op[32] = acc[mf][1][reg] * sc;
    }
  }
}

// ---------------- launcher ---------------------------------------------------------------
extern "C" void kernel_launch(void* const* d_in, const int* in_sizes, int n_in,
                              void* d_out, int out_size, void* d_ws, size_t ws_size,
                              hipStream_t stream) {
  const float* x      = (const float*)d_in[0];
  const float* style  = (const float*)d_in[1];
  const float* weight = (const float*)d_in[2];
  const float* modw   = (const float*)d_in[3];
  const float* modb   = (const float*)d_in[4];
  float* out = (float*)d_out;

  char* ws = (char*)d_ws;
  float*  s_buf = (float*)(ws + 0);
  float*  scale = (float*)(ws + 16384);
  float*  wsq   = (float*)(ws + 32768);
  __bf16* wb    = (__bf16*)(ws + 32768 + 1048576);
  __bf16* xg    = (__bf16*)(ws + 32768 + 1048576 + 9 * OUT_CH * IN_CH * 2);

  k_style<<<128, 256, 0, stream>>>(style, modw, modb, s_buf);
  k_wprep<<<1024, 256, 0, stream>>>(weight, wsq, wb);
  k_demod<<<512, 64, 0, stream>>>(s_buf, wsq, scale);
  k_xprep<<<BATCH * HW, 512, 0, stream>>>(x, s_buf, xg);
  k_conv<<<256, 512, 0, stream>>>(wb, xg, scale, out);
}

// Round 11
// 170.831 us; speedup vs baseline: 1.1464x; 1.1218x over previous
//
#include <hip/hip_runtime.h>
#include <hip/hip_bf16.h>
#include <cstdint>

#define IN_CH 512
#define OUT_CH 512
#define STYLE_DIM 512
#define BATCH 8
#define HW 64

typedef __bf16 bf16x8 __attribute__((ext_vector_type(8)));
typedef float f32x16 __attribute__((ext_vector_type(16)));

__device__ __forceinline__ void gload_lds16(const void* g, void* l) {
  __builtin_amdgcn_global_load_lds(
      (const __attribute__((address_space(1))) unsigned int*)g,
      (__attribute__((address_space(3))) unsigned int*)l,
      16, 0, 0);
}

#define WAITV(N) asm volatile("s_waitcnt vmcnt(" #N ")" ::: "memory")
#define BARRIER() do { asm volatile("" ::: "memory"); __builtin_amdgcn_s_barrier(); \
                       asm volatile("" ::: "memory"); } while (0)

// ---------------- prepass 1: s[b][ic] ----------------
__global__ void k_style(const float* __restrict__ style, const float* __restrict__ modw,
                        const float* __restrict__ modb, float* __restrict__ s_out) {
  __shared__ float st[BATCH * STYLE_DIM];
  const int tid = threadIdx.x;
  for (int i = tid; i < BATCH * STYLE_DIM; i += 256) st[i] = style[i];
  __syncthreads();
  const int ic = blockIdx.x * 4 + (tid >> 6);
  const int l = tid & 63;
  const float* mr = modw + (size_t)ic * STYLE_DIM + l * 8;
  float m[8];
  #pragma unroll
  for (int j = 0; j < 8; ++j) m[j] = mr[j];
  float accs[8];
  #pragma unroll
  for (int b = 0; b < 8; ++b) {
    const float* sb = st + b * STYLE_DIM + l * 8;
    float a = 0.f;
    #pragma unroll
    for (int j = 0; j < 8; ++j) a += m[j] * sb[j];
    accs[b] = a;
  }
  #pragma unroll
  for (int off = 32; off; off >>= 1) {
    #pragma unroll
    for (int b = 0; b < 8; ++b) accs[b] += __shfl_down(accs[b], off, 64);
  }
  if (l == 0) {
    #pragma unroll
    for (int b = 0; b < 8; ++b)
      s_out[b * IN_CH + ic] = accs[b] * 0.04419417382415922f + modb[ic];
  }
}

// ---------------- prepass 2: wsq + bf16 W, ic pre-swizzled by (oc&7) -------------------
__global__ void k_wprep(const float* __restrict__ w, float* __restrict__ wsq,
                        __bf16* __restrict__ wb) {
  const int idx = blockIdx.x * 256 + threadIdx.x;
  const int oc = idx >> 9, ic = idx & 511;
  const float* p = w + ((size_t)oc * IN_CH + ic) * 9;
  const int icw = ic ^ ((oc & 7) << 3);
  float sum = 0.f;
  #pragma unroll
  for (int t = 0; t < 9; ++t) {
    float v = p[t];
    sum += v * v;
    wb[((size_t)(t * OUT_CH) + oc) * IN_CH + icw] = (__bf16)v;
  }
  wsq[oc * IN_CH + ic] = sum;
}

// ---------------- prepass 3: demod scale ----------------
__global__ void k_demod(const float* __restrict__ s, const float* __restrict__ wsq,
                        float* __restrict__ scale) {
  const int oc = blockIdx.x;
  const int l = threadIdx.x;
  const float* wr = wsq + (size_t)oc * IN_CH + l * 8;
  float w8[8];
  #pragma unroll
  for (int j = 0; j < 8; ++j) w8[j] = wr[j];
  #pragma unroll
  for (int b = 0; b < 8; ++b) {
    const float* sb = s + b * IN_CH + l * 8;
    float acc = 0.f;
    #pragma unroll
    for (int j = 0; j < 8; ++j) { float sv = sb[j]; acc += sv * sv * w8[j]; }
    #pragma unroll
    for (int off = 32; off; off >>= 1) acc += __shfl_down(acc, off, 64);
    if (l == 0)
      scale[b * OUT_CH + oc] =
          rsqrtf(acc * (1.0f / 4608.0f) + 1e-8f) * 0.014731391274719732f;
  }
}

// ---------------- prepass 4: xg[b][ug][y][x][8] = bf16(x * s) ----------------
__global__ void k_xprep(const float* __restrict__ x, const float* __restrict__ s,
                        __bf16* __restrict__ xg) {
  const int b = blockIdx.x >> 6, y = blockIdx.x & 63;
  const int w = threadIdx.x >> 6, lane = threadIdx.x & 63;
  const float* sr = s + b * IN_CH;
  #pragma unroll
  for (int it = 0; it < 8; ++it) {
    const int ug = it * 8 + w;
    bf16x8 pk;
    #pragma unroll
    for (int j = 0; j < 8; ++j) {
      const int ic = ug * 8 + j;
      pk[j] = (__bf16)(x[(((size_t)(b * IN_CH) + ic) * HW + y) * HW + lane] * sr[ic]);
    }
    *(bf16x8*)(xg + ((((size_t)(b * 64 + ug) * HW + y) * HW + lane) * 8)) = pk;
  }
}

// ---------------- main conv: r8 schedule + unrolled taps + precomputed addressing --------
// Exactly r8's proven schedule (1 barrier/tap, counted WAITV(4), triple-buffered W,
// ks-loop with <=6 live fragments). Taps unrolled so all geometry is compile-time:
// removes ~800 cyc/tap of serial VALU addressing that sat between ds_reads and MFMAs.
__global__ __launch_bounds__(512, 2) void k_conv(
    const __bf16* __restrict__ Wg,   // [9][512][512] ic pre-swizzled by (oc&7)
    const __bf16* __restrict__ Xg,   // [8][64 ug][64 y][64 x][8]
    const float* __restrict__ scale, // [8][512] = demod*cs
    float* __restrict__ out)         // [8][512][64][64]
{
  __shared__ __attribute__((aligned(16))) __bf16 Xs[6 * 66 * 64];   // 50688 B
  __shared__ __attribute__((aligned(16))) __bf16 Wl[3][256 * 64];   // 98304 B
  __shared__ __attribute__((aligned(16))) __bf16 Dump[1024];        // 2048 B OOR sink

  const int tid = threadIdx.x;
  const int lane = tid & 63;
  const int wid = tid >> 6;
  const int wm = wid >> 2;      // oc half
  const int wn = wid & 3;       // image row within tile
  const int ln31 = lane & 31;
  const int laneK = lane >> 5;

  const int bid0 = blockIdx.x;
  const int bid = (bid0 & 7) * 32 + (bid0 >> 3);   // XCD-chunked swizzle
  const int octile = bid & 1;
  const int ptile = (bid >> 1) & 15;
  const int b = bid >> 5;
  const int oc0 = octile * 256;
  const int r0 = ptile * 4;

  auto stage_w = [&](int chunkv, int tapv, int bsel) {  // 4 gload16/thread = 32 KB
    const int ic0 = chunkv * 64;
    #pragma unroll
    for (int i = 0; i < 4; ++i) {
      const int sidx = tid + 512 * i;
      const int oc = sidx >> 3, u = sidx & 7;
      gload_lds16(Wg + (((size_t)(tapv * OUT_CH) + oc0 + oc) * IN_CH + ic0 + u * 8),
                  &Wl[bsel][oc * 64 + u * 8]);
    }
  };
  auto stage_x = [&](int chunkv) {   // ALWAYS 6 gload16/thread (fixed vmcnt bookkeeping)
    const int col = tid >> 3;        // 0..63
    const int u = tid & 7;
    const int ug = chunkv * 8 + (u ^ ((col + 1) & 7));   // swizzle via global src addr
    #pragma unroll
    for (int j = 0; j < 6; ++j) {
      const int y = r0 - 1 + j;
      const bool ok = (y >= 0 && y < HW);
      const int yc = ok ? y : 0;
      void* dst = ok ? (void*)&Xs[(j * 66 + col + 1) * 64 + u * 8]
                     : (void*)&Dump[(tid & 127) * 8];    // base + lane*16
      gload_lds16(Xg + ((((size_t)(b * 64 + ug) * HW + yc) * HW + col) * 8), dst);
    }
  };

  // zero Xs once (halo rows/cols = conv zero-padding; OOR restages go to Dump)
  {
    float4 z = {0.f, 0.f, 0.f, 0.f};
    float4* p = (float4*)Xs;
    for (int i = tid; i < 6 * 66 * 64 / 8; i += 512) p[i] = z;
  }
  __syncthreads();
  stage_x(0);               // X0(6)
  stage_w(0, 0, 0);         // +W0(4)
  stage_w(0, 1, 1);         // +W1(4) -> first tap's WAITV(4) drains X0+W0, keeps W1

  // ---- precomputed addressing (loop-invariant; const-indexed in unrolled bodies) ----
  const int kb = laneK * 8;
  const int akey8 = (ln31 & 7) << 3;
  int aoffe[4];
  #pragma unroll
  for (int ks = 0; ks < 4; ++ks) aoffe[ks] = (ks * 16 + kb) ^ akey8;
  int bele[3][4];
  #pragma unroll
  for (int dxi = 0; dxi < 3; ++dxi) {
    const int bkey8 = ((ln31 + dxi) & 7) << 3;   // col0 = ln31 + 1 + (dxi-1)
    #pragma unroll
    for (int ks = 0; ks < 4; ++ks) bele[dxi][ks] = (ks * 16 + kb) ^ bkey8;
  }
  const __bf16* __restrict__ wbp0 = &Wl[0][(128 * wm + ln31) * 64];
  const __bf16* __restrict__ wbp1 = wbp0 + 256 * 64;
  const __bf16* __restrict__ wbp2 = wbp1 + 256 * 64;
  const __bf16* __restrict__ xwb = &Xs[((wn + 1) * 66 + (ln31 + 1)) * 64];

  f32x16 acc[4][2] = {};

  // per-tap body; T compile-time, c runtime chunk index
#define TAPBODY(T) { \
    if ((T) == 8 && c == 7) { WAITV(0); } else { WAITV(4); } \
    BARRIER(); \
    const __bf16* __restrict__ wbase = ((T) % 3 == 0) ? wbp0 : ((T) % 3 == 1) ? wbp1 : wbp2; \
    const __bf16* __restrict__ xb0 = xwb + (((T) / 3 - 1) * 66 + ((T) % 3 - 1)) * 64; \
    _Pragma("unroll") \
    for (int ks = 0; ks < 4; ++ks) { \
      const int ael = aoffe[ks]; \
      const int bel = bele[(T) % 3][ks]; \
      bf16x8 av[4], bv[2]; \
      _Pragma("unroll") \
      for (int mf = 0; mf < 4; ++mf) av[mf] = *(const bf16x8*)(wbase + mf * 2048 + ael); \
      bv[0] = *(const bf16x8*)(xb0 + bel); \
      bv[1] = *(const bf16x8*)(xb0 + 32 * 64 + bel); \
      __builtin_amdgcn_s_setprio(1); \
      _Pragma("unroll") \
      for (int mf = 0; mf < 4; ++mf) { \
        acc[mf][0] = __builtin_amdgcn_mfma_f32_32x32x16_bf16(av[mf], bv[0], acc[mf][0], 0, 0, 0); \
        acc[mf][1] = __builtin_amdgcn_mfma_f32_32x32x16_bf16(av[mf], bv[1], acc[mf][1], 0, 0, 0); \
      } \
      __builtin_amdgcn_s_setprio(0); \
    } \
    if ((T) == 8) { \
      if (c < 7) { BARRIER(); stage_x(c + 1); stage_w(c + 1, 1, 1); } \
    } else if ((T) <= 6) { \
      stage_w(c, (T) + 2, ((T) + 2) % 3); \
    } else { /* T == 7 */ \
      if (c < 7) stage_w(c + 1, 0, 0); \
    } \
  }

  #pragma unroll 1
  for (int c = 0; c < 8; ++c) {
    TAPBODY(0) TAPBODY(1) TAPBODY(2)
    TAPBODY(3) TAPBODY(4) TAPBODY(5)
    TAPBODY(6) TAPBODY(7) TAPBODY(8)
  }

  // epilogue: out = acc * (demod*cs), NCHW
  const int y = r0 + wn;
  #pragma unroll
  for (int mf = 0; mf < 4; ++mf) {
    #pragma unroll
    for (int reg = 0; reg < 16; ++reg) {
      const int rowid = (reg & 3) + 8 * (reg >> 2) + 4 * laneK;
      const int oc = oc0 + 128 * wm + 32 * mf + rowid;
      const float sc = scale[b * OUT_CH + oc];
      float* op = out + (((size_t)(b * OUT_CH + oc) * HW + y) * HW) + ln31;
      op[0] = acc[mf][0][reg] * sc;
      op[32] = acc[mf][1][reg] * sc;
    }
  }
}

// ---------------- launcher ---------------------------------------------------------------
extern "C" void kernel_launch(void* const* d_in, const int* in_sizes, int n_in,
                              void* d_out, int out_size, void* d_ws, size_t ws_size,
                              hipStream_t stream) {
  const float* x      = (const float*)d_in[0];
  const float* style  = (const float*)d_in[1];
  const float* weight = (const float*)d_in[2];
  const float* modw   = (const float*)d_in[3];
  const float* modb   = (const float*)d_in[4];
  float* out = (float*)d_out;

  char* ws = (char*)d_ws;
  float*  s_buf = (float*)(ws + 0);
  float*  scale = (float*)(ws + 16384);
  float*  wsq   = (float*)(ws + 32768);
  __bf16* wb    = (__bf16*)(ws + 32768 + 1048576);
  __bf16* xg    = (__bf16*)(ws + 32768 + 1048576 + 9 * OUT_CH * IN_CH * 2);

  k_style<<<128, 256, 0, stream>>>(style, modw, modb, s_buf);
  k_wprep<<<1024, 256, 0, stream>>>(weight, wsq, wb);
  k_demod<<<512, 64, 0, stream>>>(s_buf, wsq, scale);
  k_xprep<<<BATCH * HW, 512, 0, stream>>>(x, s_buf, xg);
  k_conv<<<256, 512, 0, stream>>>(wb, xg, scale, out);
}